// Round 9
// baseline (44.921 us; speedup 1.0000x reference)
//
#include <hip/hip_runtime.h>
#include <stdint.h>

#define BATCH 128
#define MAXN 1024
#define NF 9
#define DIM 256
#define NCLS 10

// Combined-table layout (rows of 256):
//  sec0: [0,119)    field0
//  sec1: [119,179)  fields1,2   idx = i1*12+i2
//  sec2: [179,299)  fields3,4   idx = i3*10+i4
//  sec3: [299,443)  fields5..8  idx = ((i5*6+i6)*2+i7)*2+i8
#define BASE1 119
#define BASE2 179
#define BASE3 299
#define QROWS 443

#define TBLK 114                  // table-prep blocks (3 cls + 111 Q)
#define PACKBLK (BATCH * MAXN / 256)  // 512 index-pack blocks

typedef __attribute__((ext_vector_type(4))) float f32x4;
typedef __attribute__((ext_vector_type(2))) uint32_t u32x2;

__device__ __forceinline__ ushort f32_to_bf16_rne(float x) {
  uint32_t u = __float_as_uint(x);
  u += 0x7fffu + ((u >> 16) & 1u);
  return (ushort)(u >> 16);
}

__device__ __forceinline__ f32x4 bf4_to_f32x4(u32x2 v) {
  f32x4 r;
  r.x = __uint_as_float(v.x << 16);
  r.y = __uint_as_float(v.x & 0xffff0000u);
  r.z = __uint_as_float(v.y << 16);
  r.w = __uint_as_float(v.y & 0xffff0000u);
  return r;
}

// ---------------------------------------------------------------------------
// Prep: 114 table blocks + 512 index-pack blocks (independent work, one grid).
//  bid in [0,3):       class rows (f32): clsT[c][o] = lin_b[o] + W2[o]·rxn_emb[c]
//  bid in [3,114):     Q rows (bf16):    Q[q][o]    = W1[o]·S_q
//  bid in [114,626):   jpack[node] = int4{j0,j1,j2,j3} — the 4 combined-table
//                      rows per node, folding 9 raw indices into one 16B load
//                      for the main kernel (kills the 9-uniform-load chain).
// ---------------------------------------------------------------------------
__global__ __launch_bounds__(256) void prep_kernel(
    const float* __restrict__ rxn_emb, const float* __restrict__ lin_w,
    const float* __restrict__ lin_b, const float* __restrict__ atom_emb,
    const int* __restrict__ node_feat,
    ushort* __restrict__ Qb, float* __restrict__ clsT, int4* __restrict__ jpack)
{
  const int bid = blockIdx.x;
  const int t = threadIdx.x;

  if (bid >= TBLK) {  // ---- index-pack path ----
    const int node = (bid - TBLK) * 256 + t;
    const int* p = node_feat + (size_t)node * NF;
    int4 jv;
    jv.x = p[0];
    jv.y = BASE1 + p[1] * 12 + p[2];
    jv.z = BASE2 + p[3] * 10 + p[4];
    jv.w = BASE3 + ((p[5] * 6 + p[6]) * 2 + p[7]) * 2 + p[8];
    jpack[node] = jv;
    return;
  }

  // ---- table path (proven shape: 4 rows/block, one W sweep amortized) ----
  __shared__ float S[4][DIM];
  const bool isCls = bid < 3;
  const int row0 = isCls ? bid * 4 : (bid - 3) * 4;
  const int rmax = isCls ? NCLS : QROWS;
  const int nrows = (rmax - row0 < 4) ? (rmax - row0) : 4;

#pragma unroll
  for (int r = 0; r < 4; ++r) {
    float v = 0.f;
    if (r < nrows) {
      const int q = row0 + r;
      if (isCls) {
        v = rxn_emb[q * DIM + t];
      } else if (q < BASE1) {
        v = atom_emb[q * DIM + t];
      } else if (q < BASE2) {
        int x = q - BASE1;
        v = atom_emb[(119 + x / 12) * DIM + t] + atom_emb[(124 + x % 12) * DIM + t];
      } else if (q < BASE3) {
        int x = q - BASE2;
        v = atom_emb[(136 + x / 10) * DIM + t] + atom_emb[(148 + x % 10) * DIM + t];
      } else {
        int x = q - BASE3;
        int i8 = x & 1, i7 = (x >> 1) & 1, y = x >> 2;
        v = atom_emb[(158 + y / 6) * DIM + t] + atom_emb[(164 + y % 6) * DIM + t]
          + atom_emb[(170 + i7) * DIM + t] + atom_emb[(172 + i8) * DIM + t];
      }
    }
    S[r][t] = v;
  }
  __syncthreads();

  const float* wrow = lin_w + (size_t)t * 2 * DIM + (isCls ? DIM : 0);
  const float init = isCls ? lin_b[t] : 0.f;
  float a0 = init, a1 = init, a2 = init, a3 = init;
#pragma unroll 4
  for (int d = 0; d < DIM; d += 4) {
    float4 w4 = *(const float4*)(wrow + d);
    a0 += w4.x * S[0][d] + w4.y * S[0][d + 1] + w4.z * S[0][d + 2] + w4.w * S[0][d + 3];
    a1 += w4.x * S[1][d] + w4.y * S[1][d + 1] + w4.z * S[1][d + 2] + w4.w * S[1][d + 3];
    a2 += w4.x * S[2][d] + w4.y * S[2][d + 1] + w4.z * S[2][d + 2] + w4.w * S[2][d + 3];
    a3 += w4.x * S[3][d] + w4.y * S[3][d + 1] + w4.z * S[3][d + 2] + w4.w * S[3][d + 3];
  }
  if (isCls) {
    if (0 < nrows) clsT[(row0 + 0) * DIM + t] = a0;
    if (1 < nrows) clsT[(row0 + 1) * DIM + t] = a1;
    if (2 < nrows) clsT[(row0 + 2) * DIM + t] = a2;
    if (3 < nrows) clsT[(row0 + 3) * DIM + t] = a3;
  } else {
    if (0 < nrows) Qb[(row0 + 0) * DIM + t] = f32_to_bf16_rne(a0);
    if (1 < nrows) Qb[(row0 + 1) * DIM + t] = f32_to_bf16_rne(a1);
    if (2 < nrows) Qb[(row0 + 2) * DIM + t] = f32_to_bf16_rne(a2);
    if (3 < nrows) Qb[(row0 + 3) * DIM + t] = f32_to_bf16_rne(a3);
  }
}

// ---------------------------------------------------------------------------
// Main: 2048 blocks x 256 threads; wave = 16 node slots. SINGLE STRUCTURAL
// CHANGE vs round 8: packed indices. Per node now 6 VMEM (1 idx + 4 gathers
// + 1 store), was 14 (9 idx + 4 + 1), and index loads are INDEPENDENT across
// the strip — no per-node load->load chain, so gathers/stores pipeline at
// full ILP(16) depth and store-issue density rises toward fill-kernel rate.
// bf16 Q, cached gathers, plain stores, three wave-uniform paths.
// ---------------------------------------------------------------------------
__global__ __launch_bounds__(256) void main_kernel(
    const int4* __restrict__ jpack, const int* __restrict__ num_nodes,
    const int* __restrict__ rxn_class,
    const ushort* __restrict__ Qb, const float* __restrict__ clsT,
    float* __restrict__ out)
{
  const int tid = threadIdx.x;
  const int lane = tid & 63;
  const int w = __builtin_amdgcn_readfirstlane(tid >> 6);
  const int wid = blockIdx.x * 4 + w;   // 0..8191
  const int b = wid >> 6;               // 64 waves per batch
  const int n0 = (wid & 63) << 4;       // 16 nodes per wave
  const int nn = num_nodes[b];

  const f32x4 cf = ((const f32x4*)clsT)[rxn_class[b] * 64 + lane];
  f32x4* __restrict__ outp = (f32x4*)out + ((size_t)(b * MAXN + n0)) * 64 + lane;

  if (n0 >= nn) {  // fully masked strip
#pragma unroll
    for (int i = 0; i < 16; ++i)
      outp[i * 64] = cf;
    return;
  }

  const int4* __restrict__ jp = jpack + (size_t)b * MAXN + n0;
  const u32x2* __restrict__ Q2 = (const u32x2*)Qb;

  if (n0 + 16 <= nn) {  // fully valid strip — independent node pipelines
#pragma unroll 8
    for (int i = 0; i < 16; ++i) {
      const int4 jv = jp[i];
      const u32x2 v0 = Q2[jv.x * 64 + lane];
      const u32x2 v1 = Q2[jv.y * 64 + lane];
      const u32x2 v2 = Q2[jv.z * 64 + lane];
      const u32x2 v3 = Q2[jv.w * 64 + lane];
      const f32x4 s = (bf4_to_f32x4(v0) + bf4_to_f32x4(v1))
                    + (bf4_to_f32x4(v2) + bf4_to_f32x4(v3));
      outp[i * 64] = cf + s;
    }
    return;
  }

  // partial strip (<=1 per batch): branchless float-mask
#pragma unroll 8
  for (int i = 0; i < 16; ++i) {
    const int4 jv = jp[i];
    const u32x2 v0 = Q2[jv.x * 64 + lane];
    const u32x2 v1 = Q2[jv.y * 64 + lane];
    const u32x2 v2 = Q2[jv.z * 64 + lane];
    const u32x2 v3 = Q2[jv.w * 64 + lane];
    const float m = (n0 + i < nn) ? 1.f : 0.f;
    const f32x4 s = (bf4_to_f32x4(v0) + bf4_to_f32x4(v1))
                  + (bf4_to_f32x4(v2) + bf4_to_f32x4(v3));
    outp[i * 64] = cf + m * s;
  }
}

extern "C" void kernel_launch(void* const* d_in, const int* in_sizes, int n_in,
                              void* d_out, int out_size, void* d_ws, size_t ws_size,
                              hipStream_t stream) {
  const int* node_feat = (const int*)d_in[0];
  const int* num_nodes = (const int*)d_in[1];
  const int* rxn_class = (const int*)d_in[2];
  const float* atom_emb = (const float*)d_in[3];
  const float* rxn_emb = (const float*)d_in[4];
  const float* lin_w = (const float*)d_in[5];
  const float* lin_b = (const float*)d_in[6];
  float* outp = (float*)d_out;

  // workspace: Qb (226816 B) | clsT (10240 B) | pad | jpack (128*1024*16 B)
  ushort* Qb = (ushort*)d_ws;
  float* clsT = (float*)((char*)d_ws + QROWS * DIM * sizeof(ushort));
  int4* jpack = (int4*)((char*)d_ws + 262144);  // 256KB-aligned offset

  prep_kernel<<<TBLK + PACKBLK, 256, 0, stream>>>(rxn_emb, lin_w, lin_b,
                                                  atom_emb, node_feat,
                                                  Qb, clsT, jpack);
  main_kernel<<<2048, 256, 0, stream>>>(jpack, num_nodes, rxn_class,
                                        Qb, clsT, outp);
}

// Round 10
// 40.859 us; speedup vs baseline: 1.0994x; 1.0994x over previous
//
#include <hip/hip_runtime.h>
#include <stdint.h>

#define BATCH 128
#define MAXN 1024
#define NF 9
#define DIM 256
#define NCLS 10

// Combined-table sections (rows of 256):
#define BASE1 119
#define BASE2 179
#define BASE3 299
#define QROWS 443

#define TBLK 114                      // table-prep blocks (3 cls + 111 Q)
#define PACKBLK (BATCH * MAXN / 256)  // 512 index-pack blocks

#define NSL 4           // column slices
#define SCOL 64         // columns per slice
#define SLICE_U4 3544   // 443*64*2B / 16B per uint4

typedef __attribute__((ext_vector_type(4))) float f32x4;
typedef __attribute__((ext_vector_type(2))) uint32_t u32x2;

__device__ __forceinline__ ushort f32_to_bf16_rne(float x) {
  uint32_t u = __float_as_uint(x);
  u += 0x7fffu + ((u >> 16) & 1u);
  return (ushort)(u >> 16);
}

__device__ __forceinline__ f32x4 bf4_to_f32x4(u32x2 v) {
  f32x4 r;
  r.x = __uint_as_float(v.x << 16);
  r.y = __uint_as_float(v.x & 0xffff0000u);
  r.z = __uint_as_float(v.y << 16);
  r.w = __uint_as_float(v.y & 0xffff0000u);
  return r;
}

// ---------------------------------------------------------------------------
// Prep: 114 table blocks + 512 index-pack blocks.
//  Qb is written SLICE-MAJOR: Qb[slice][row][col] (bf16) so the main kernel
//  can stage one 56.7KB slice contiguously into LDS.
//  clsT[c][o] f32 as before; jpack[node] = int4 of 4 combined-table rows.
// ---------------------------------------------------------------------------
__global__ __launch_bounds__(256) void prep_kernel(
    const float* __restrict__ rxn_emb, const float* __restrict__ lin_w,
    const float* __restrict__ lin_b, const float* __restrict__ atom_emb,
    const int* __restrict__ node_feat,
    ushort* __restrict__ Qb, float* __restrict__ clsT, int4* __restrict__ jpack)
{
  const int bid = blockIdx.x;
  const int t = threadIdx.x;

  if (bid >= TBLK) {  // ---- index-pack path ----
    const int node = (bid - TBLK) * 256 + t;
    const int* p = node_feat + (size_t)node * NF;
    int4 jv;
    jv.x = p[0];
    jv.y = BASE1 + p[1] * 12 + p[2];
    jv.z = BASE2 + p[3] * 10 + p[4];
    jv.w = BASE3 + ((p[5] * 6 + p[6]) * 2 + p[7]) * 2 + p[8];
    jpack[node] = jv;
    return;
  }

  // ---- table path: 4 rows/block, one W sweep amortized ----
  __shared__ float S[4][DIM];
  const bool isCls = bid < 3;
  const int row0 = isCls ? bid * 4 : (bid - 3) * 4;
  const int rmax = isCls ? NCLS : QROWS;
  const int nrows = (rmax - row0 < 4) ? (rmax - row0) : 4;

#pragma unroll
  for (int r = 0; r < 4; ++r) {
    float v = 0.f;
    if (r < nrows) {
      const int q = row0 + r;
      if (isCls) {
        v = rxn_emb[q * DIM + t];
      } else if (q < BASE1) {
        v = atom_emb[q * DIM + t];
      } else if (q < BASE2) {
        int x = q - BASE1;
        v = atom_emb[(119 + x / 12) * DIM + t] + atom_emb[(124 + x % 12) * DIM + t];
      } else if (q < BASE3) {
        int x = q - BASE2;
        v = atom_emb[(136 + x / 10) * DIM + t] + atom_emb[(148 + x % 10) * DIM + t];
      } else {
        int x = q - BASE3;
        int i8 = x & 1, i7 = (x >> 1) & 1, y = x >> 2;
        v = atom_emb[(158 + y / 6) * DIM + t] + atom_emb[(164 + y % 6) * DIM + t]
          + atom_emb[(170 + i7) * DIM + t] + atom_emb[(172 + i8) * DIM + t];
      }
    }
    S[r][t] = v;
  }
  __syncthreads();

  const float* wrow = lin_w + (size_t)t * 2 * DIM + (isCls ? DIM : 0);
  const float init = isCls ? lin_b[t] : 0.f;
  float a0 = init, a1 = init, a2 = init, a3 = init;
#pragma unroll 4
  for (int d = 0; d < DIM; d += 4) {
    float4 w4 = *(const float4*)(wrow + d);
    a0 += w4.x * S[0][d] + w4.y * S[0][d + 1] + w4.z * S[0][d + 2] + w4.w * S[0][d + 3];
    a1 += w4.x * S[1][d] + w4.y * S[1][d + 1] + w4.z * S[1][d + 2] + w4.w * S[1][d + 3];
    a2 += w4.x * S[2][d] + w4.y * S[2][d + 1] + w4.z * S[2][d + 2] + w4.w * S[2][d + 3];
    a3 += w4.x * S[3][d] + w4.y * S[3][d + 1] + w4.z * S[3][d + 2] + w4.w * S[3][d + 3];
  }
  if (isCls) {
    if (0 < nrows) clsT[(row0 + 0) * DIM + t] = a0;
    if (1 < nrows) clsT[(row0 + 1) * DIM + t] = a1;
    if (2 < nrows) clsT[(row0 + 2) * DIM + t] = a2;
    if (3 < nrows) clsT[(row0 + 3) * DIM + t] = a3;
  } else {
    // slice-major: Qb[(t>>6)*QROWS*SCOL + row*SCOL + (t&63)]
    const int s = t >> 6, c = t & 63;
    if (0 < nrows) Qb[(size_t)s * QROWS * SCOL + (row0 + 0) * SCOL + c] = f32_to_bf16_rne(a0);
    if (1 < nrows) Qb[(size_t)s * QROWS * SCOL + (row0 + 1) * SCOL + c] = f32_to_bf16_rne(a1);
    if (2 < nrows) Qb[(size_t)s * QROWS * SCOL + (row0 + 2) * SCOL + c] = f32_to_bf16_rne(a2);
    if (3 < nrows) Qb[(size_t)s * QROWS * SCOL + (row0 + 3) * SCOL + c] = f32_to_bf16_rne(a3);
  }
}

// ---------------------------------------------------------------------------
// Main (STRUCTURAL CHANGE): table gathers moved to LDS. Block = 1024 threads
// (16 waves), owns one (slice, batch, node-quarter): stages its 56.7KB table
// slice into LDS once, then per node: 1 idx load + 4 ds_read_b64 + 1 f32x4
// store. Per-node VMEM drops 6 -> 2; table reads ride the lgkmcnt pipe,
// fully overlapped with the vmcnt store stream (the suspected contention).
// 2 blocks/CU co-resident (113KB LDS) so staging hides under compute.
// Lane l: node-group nd = l>>4, col c = l&15 (4 nodes per pass).
// All-masked quarters skip staging and pure-fill the class row.
// ---------------------------------------------------------------------------
__global__ __launch_bounds__(1024, 8) void main_kernel(
    const int4* __restrict__ jpack, const int* __restrict__ num_nodes,
    const int* __restrict__ rxn_class,
    const ushort* __restrict__ Qb, const float* __restrict__ clsT,
    float* __restrict__ out)
{
  __shared__ ushort Ls[QROWS * SCOL];  // 56704 B

  const int tid = threadIdx.x;
  const int bid = blockIdx.x;
  const int s = bid & 3;                 // slice
  const int b = (bid >> 2) & 127;        // batch
  const int q = bid >> 9;                // node quarter (0..3)
  const int n0_blk = q * 256;
  const int nn = num_nodes[b];
  const int cls = rxn_class[b];
  const f32x4* __restrict__ clsT4 = (const f32x4*)clsT;
  f32x4* __restrict__ out4 = (f32x4*)out;

  if (n0_blk >= nn) {
    // fully masked quarter: pure fill of 256 nodes x 64 cols with class row
    const f32x4 cf = clsT4[cls * 64 + s * 16 + (tid & 15)];
    const size_t base = (size_t)(b * MAXN + n0_blk) * 64 + s * 16;
#pragma unroll
    for (int k = 0; k < 4; ++k) {
      const int idx = tid + k * 1024;          // 0..4095
      const int node = idx >> 4, c4 = idx & 15;
      out4[base + (size_t)node * 64 + c4] = cf;
    }
    return;
  }

  // stage slice into LDS (contiguous copy, uint4 granules)
  {
    const uint4* __restrict__ src = (const uint4*)(Qb + (size_t)s * QROWS * SCOL);
    uint4* dst = (uint4*)Ls;
    for (int i = tid; i < SLICE_U4; i += 1024) dst[i] = src[i];
  }
  __syncthreads();

  const int w = __builtin_amdgcn_readfirstlane(tid >> 6);  // wave 0..15
  const int lane = tid & 63;
  const int nd = lane >> 4;     // node sub-index 0..3
  const int c = lane & 15;      // col quad 0..15
  const int n0 = n0_blk + w * 16;

  const f32x4 cf = clsT4[cls * 64 + s * 16 + c];
  const u32x2* __restrict__ L2p = (const u32x2*)Ls;  // row*SCOL/4 + c
  const int4* __restrict__ jp = jpack + (size_t)b * MAXN;
  const size_t obase = (size_t)(b * MAXN) * 64 + s * 16 + c;

  if (n0 >= nn) {  // masked wave: fill its 16 nodes
#pragma unroll
    for (int p = 0; p < 4; ++p) {
      const int n = n0 + p * 4 + nd;
      out4[obase + (size_t)n * 64] = cf;
    }
    return;
  }

  if (n0 + 16 <= nn) {  // fully valid wave
#pragma unroll
    for (int p = 0; p < 4; ++p) {
      const int n = n0 + p * 4 + nd;
      const int4 jv = jp[n];
      const u32x2 v0 = L2p[jv.x * 16 + c];
      const u32x2 v1 = L2p[jv.y * 16 + c];
      const u32x2 v2 = L2p[jv.z * 16 + c];
      const u32x2 v3 = L2p[jv.w * 16 + c];
      const f32x4 sum = (bf4_to_f32x4(v0) + bf4_to_f32x4(v1))
                      + (bf4_to_f32x4(v2) + bf4_to_f32x4(v3));
      out4[obase + (size_t)n * 64] = cf + sum;
    }
    return;
  }

  // partial wave: branchless per-lane mask
#pragma unroll
  for (int p = 0; p < 4; ++p) {
    const int n = n0 + p * 4 + nd;
    const int4 jv = jp[n];
    const u32x2 v0 = L2p[jv.x * 16 + c];
    const u32x2 v1 = L2p[jv.y * 16 + c];
    const u32x2 v2 = L2p[jv.z * 16 + c];
    const u32x2 v3 = L2p[jv.w * 16 + c];
    const float m = (n < nn) ? 1.f : 0.f;
    const f32x4 sum = (bf4_to_f32x4(v0) + bf4_to_f32x4(v1))
                    + (bf4_to_f32x4(v2) + bf4_to_f32x4(v3));
    out4[obase + (size_t)n * 64] = cf + m * sum;
  }
}

extern "C" void kernel_launch(void* const* d_in, const int* in_sizes, int n_in,
                              void* d_out, int out_size, void* d_ws, size_t ws_size,
                              hipStream_t stream) {
  const int* node_feat = (const int*)d_in[0];
  const int* num_nodes = (const int*)d_in[1];
  const int* rxn_class = (const int*)d_in[2];
  const float* atom_emb = (const float*)d_in[3];
  const float* rxn_emb = (const float*)d_in[4];
  const float* lin_w = (const float*)d_in[5];
  const float* lin_b = (const float*)d_in[6];
  float* outp = (float*)d_out;

  // workspace: Qb slice-major (226816 B) | clsT (10240 B) | pad | jpack (2 MB)
  ushort* Qb = (ushort*)d_ws;
  float* clsT = (float*)((char*)d_ws + QROWS * DIM * sizeof(ushort));
  int4* jpack = (int4*)((char*)d_ws + 262144);

  prep_kernel<<<TBLK + PACKBLK, 256, 0, stream>>>(rxn_emb, lin_w, lin_b,
                                                  atom_emb, node_feat,
                                                  Qb, clsT, jpack);
  main_kernel<<<NSL * BATCH * 4, 1024, 0, stream>>>(jpack, num_nodes, rxn_class,
                                                    Qb, clsT, outp);
}